// Round 5
// baseline (2800.770 us; speedup 1.0000x reference)
//
#include <hip/hip_runtime.h>
#include <hip/hip_fp16.h>
#include <stdint.h>

// Problem constants
#define BB 64
#define SS 512
#define EE 128
#define HH 256
#define KK 20
#define NEGV -9999.0f
#define SOS_IDX 19

typedef unsigned int u32;

__device__ __forceinline__ float sigm(float x){ return 1.0f / (1.0f + __expf(-x)); }
__device__ __forceinline__ float tanh_fast(float x){
  float e = __expf(2.f * x);          // x->+inf: e=inf -> 1; x->-inf: e=0 -> -1
  return 1.f - 2.f / (e + 1.f);
}

// 4 packed fma: w (uint4 = 8 f16) * h (4 half2 in regs) -> 4 half2 accs
__device__ __forceinline__ void pk4(uint4 w, const __half2* hp,
                                    __half2& a0, __half2& a1, __half2& a2, __half2& a3){
  __half2 w0 = *(__half2*)&w.x, w1 = *(__half2*)&w.y, w2 = *(__half2*)&w.z, w3 = *(__half2*)&w.w;
  a0 = __hfma2(w0, hp[0], a0);
  a1 = __hfma2(w1, hp[1], a1);
  a2 = __hfma2(w2, hp[2], a2);
  a3 = __hfma2(w3, hp[3], a3);
}
__device__ __forceinline__ float flushacc(__half2& a0, __half2& a1, __half2& a2, __half2& a3){
  float2 f0 = __half22float2(a0), f1 = __half22float2(a1);
  float2 f2 = __half22float2(a2), f3 = __half22float2(a3);
  __half2 z = __floats2half2_rn(0.f, 0.f);
  a0 = z; a1 = z; a2 = z; a3 = z;
  return ((f0.x + f0.y) + (f1.x + f1.y)) + ((f2.x + f2.y) + (f3.x + f3.y));
}

// ---- K0a: pack W_hh (f32 [1024][256]) -> f16 wp[d][chunk(32)][row(1024)][8]
// chunk c covers k = 8c..8c+7.
__global__ void prep_whh(const float* __restrict__ whh_f, const float* __restrict__ whh_b,
                         __half* __restrict__ wp){
  int id = blockIdx.x * 256 + threadIdx.x;      // 2*1024*256 = 524288
  if (id >= 524288) return;
  int d = id >> 18;
  int rem = id & 262143;
  int row = rem >> 8;
  int k = rem & 255;
  const float* w = d ? whh_b : whh_f;
  wp[(((size_t)d * 32 + (k >> 3)) * 1024 + row) * 8 + (k & 7)] = __float2half(w[row * 256 + k]);
}

// ---- K0b: transpose W_ih -> wt[k(128)][2048] f32 (cols 0..1023 fwd, 1024..2047 bwd)
__global__ void prep_wih(const float* __restrict__ wih_f, const float* __restrict__ wih_b,
                         float* __restrict__ wt){
  int id = blockIdx.x * 256 + threadIdx.x;      // 2*1024*128 = 262144
  if (id >= 262144) return;
  int d = id >> 17;
  int rem = id & 131071;
  int col = rem >> 7;
  int k = rem & 127;
  const float* w = d ? wih_b : wih_f;
  wt[(size_t)k * 2048 + d * 1024 + col] = w[col * 128 + k];
}

// ---- K1: xg = embed[word] @ W_ih.T + b, both dirs, stored f16.
__global__ __launch_bounds__(256) void xg_gemm(const int* __restrict__ word_seq,
    const float* __restrict__ embed, const float* __restrict__ wt,
    const float* __restrict__ b_f, const float* __restrict__ b_b,
    __half* __restrict__ xg){
  __shared__ __align__(16) float xs[16][128];
  int rb = blockIdx.x >> 1, cb = blockIdx.x & 1;
  int tid = threadIdx.x;
  {
    int r = tid >> 4, kq = (tid & 15) * 8;
    int bs = rb * 16 + r;
    int w = word_seq[bs];
    const float* er = embed + (size_t)w * 128 + kq;
    float4 a = *(const float4*)er;
    float4 b = *(const float4*)(er + 4);
    *(float4*)&xs[r][kq] = a;
    *(float4*)&xs[r][kq + 4] = b;
  }
  __syncthreads();
  int co = tid * 4;
  const float* bias = cb ? b_b : b_f;
  float4 bv = *(const float4*)(bias + co);
  float4 acc[16];
  #pragma unroll
  for (int r = 0; r < 16; r++) acc[r] = bv;
  const float* wptr = wt + cb * 1024 + co;
  for (int k = 0; k < 128; k++){
    float4 w4 = *(const float4*)(wptr + (size_t)k * 2048);
    #pragma unroll
    for (int r = 0; r < 16; r++){
      float xv = xs[r][k];
      acc[r].x += xv * w4.x; acc[r].y += xv * w4.y;
      acc[r].z += xv * w4.z; acc[r].w += xv * w4.w;
    }
  }
  __half* base = xg + (size_t)cb * ((size_t)BB * SS * 1024);
  #pragma unroll
  for (int r = 0; r < 16; r++){
    int bs = rb * 16 + r;
    __half* o = base + (size_t)bs * 1024 + co;
    __half2 p0 = __floats2half2_rn(acc[r].x, acc[r].y);
    __half2 p1 = __floats2half2_rn(acc[r].z, acc[r].w);
    uint2 st; st.x = *(u32*)&p0; st.y = *(u32*)&p1;
    *(uint2*)o = st;
  }
}

// ---- K2: sequential LSTM, one WG (256 thr = 4 waves, 1 wave/SIMD) per (batch, dir).
// Thread t owns ALL FOUR gate rows {t, t+256, t+512, t+768} = gates i,f,g,o of
// hidden unit t -> no gate exchange, c/h updated locally, ONE barrier per step.
// Weight tiers per row (32 chunks of 8 f16):
//   chunks 0..15  : VGPR (4 rows x 16 = 64 uint4 = 256 regs; cap ~512 at 1 wave/EU)
//   chunks 16..23 : LDS thread-private (32 slots x 256 thr x 16 B = 128 KB)
//   chunks 24..31 : streamed from L2, 4 rolling 8-reg batches (peak 16 uint4)
// h: f16 double-buffer in LDS (2x512 B), read as 32 b128 broadcasts per thread.
__global__ __launch_bounds__(256, 1) void lstm_seq(const int* __restrict__ lengths,
    const __half* __restrict__ wp, const __half* __restrict__ xg,
    float* __restrict__ rnn){
  extern __shared__ __align__(16) char smem[];
  u32*    wl = (u32*)smem;                       // 32 slots * 256 * 16 B = 131072
  __half* hb = (__half*)(smem + 131072);         // 2 * 256 f16 = 1024 B

  int bx = blockIdx.x;
  int b = bx & 63, d = bx >> 6;
  int tid = threadIdx.x;
  int l = lengths[b];
  const uint4* wp4 = (const uint4*)(wp + (size_t)d * (32 * 1024 * 8));

  // VGPR-resident chunks 0..15 for the 4 rows
  uint4 wr[4][16];
  #pragma unroll
  for (int g = 0; g < 4; g++){
    int row = tid + g * 256;
    #pragma unroll
    for (int c = 0; c < 16; c++) wr[g][c] = wp4[c * 1024 + row];
  }
  // LDS chunks 16..23, slot = g*8 + (c-16)
  #pragma unroll
  for (int g = 0; g < 4; g++){
    int row = tid + g * 256;
    #pragma unroll
    for (int c = 0; c < 8; c++){
      uint4 v = wp4[(16 + c) * 1024 + row];
      *(uint4*)&wl[((g * 8 + c) * 256 + tid) * 4] = v;
    }
  }
  hb[tid] = __float2half(0.f);                  // buffer 0
  float cc = 0.f;
  const __half* xgd = xg + ((size_t)d * BB * SS + (size_t)b * SS) * 1024;
  float* rbp = rnn + (size_t)b * SS * 512 + d * 256;
  for (int s = l; s < SS; s++) rbp[(size_t)s * 512 + tid] = 0.f;
  int cur = 0;
  __syncthreads();

  for (int t = 0; t < l; t++){
    int s = d ? (l - 1 - t) : t;
    // xg for the 4 gate rows (issued early, consumed at the end)
    const __half* xr = xgd + (size_t)s * 1024 + tid;
    float xv0 = __half2float(xr[0]);
    float xv1 = __half2float(xr[256]);
    float xv2 = __half2float(xr[512]);
    float xv3 = __half2float(xr[768]);
    const __half* hc = &hb[cur * 256];
    // prefetch stream batches A(24,25) and B(26,27)
    uint4 sA[4][2], sB[4][2];
    #pragma unroll
    for (int g = 0; g < 4; g++){
      int row = tid + g * 256;
      sA[g][0] = wp4[24 * 1024 + row];
      sA[g][1] = wp4[25 * 1024 + row];
      sB[g][0] = wp4[26 * 1024 + row];
      sB[g][1] = wp4[27 * 1024 + row];
    }
    __half2 z = __floats2half2_rn(0.f, 0.f);
    __half2 acc[4][4];
    #pragma unroll
    for (int g = 0; g < 4; g++){
      acc[g][0] = z; acc[g][1] = z; acc[g][2] = z; acc[g][3] = z;
    }
    float fa[4];
    // phase V: chunks 0..15 from VGPR
    #pragma unroll
    for (int c = 0; c < 16; c++){
      uint4 hv = *(const uint4*)&hc[c * 8];
      const __half2* hp = (const __half2*)&hv;
      #pragma unroll
      for (int g = 0; g < 4; g++) pk4(wr[g][c], hp, acc[g][0], acc[g][1], acc[g][2], acc[g][3]);
    }
    #pragma unroll
    for (int g = 0; g < 4; g++) fa[g] = flushacc(acc[g][0], acc[g][1], acc[g][2], acc[g][3]);
    // phase L: chunks 16..23 from LDS
    #pragma unroll
    for (int c = 0; c < 8; c++){
      uint4 hv = *(const uint4*)&hc[(16 + c) * 8];
      const __half2* hp = (const __half2*)&hv;
      #pragma unroll
      for (int g = 0; g < 4; g++){
        uint4 wv = *(const uint4*)&wl[((g * 8 + c) * 256 + tid) * 4];
        pk4(wv, hp, acc[g][0], acc[g][1], acc[g][2], acc[g][3]);
      }
    }
    #pragma unroll
    for (int g = 0; g < 4; g++) fa[g] += flushacc(acc[g][0], acc[g][1], acc[g][2], acc[g][3]);
    // phase S: chunks 24..31 streamed
    {
      uint4 hv = *(const uint4*)&hc[24 * 8];
      const __half2* hp = (const __half2*)&hv;
      #pragma unroll
      for (int g = 0; g < 4; g++) pk4(sA[g][0], hp, acc[g][0], acc[g][1], acc[g][2], acc[g][3]);
      uint4 hv2 = *(const uint4*)&hc[25 * 8];
      const __half2* hp2 = (const __half2*)&hv2;
      #pragma unroll
      for (int g = 0; g < 4; g++) pk4(sA[g][1], hp2, acc[g][0], acc[g][1], acc[g][2], acc[g][3]);
    }
    // prefetch C(28,29) into sA
    #pragma unroll
    for (int g = 0; g < 4; g++){
      int row = tid + g * 256;
      sA[g][0] = wp4[28 * 1024 + row];
      sA[g][1] = wp4[29 * 1024 + row];
    }
    {
      uint4 hv = *(const uint4*)&hc[26 * 8];
      const __half2* hp = (const __half2*)&hv;
      #pragma unroll
      for (int g = 0; g < 4; g++) pk4(sB[g][0], hp, acc[g][0], acc[g][1], acc[g][2], acc[g][3]);
      uint4 hv2 = *(const uint4*)&hc[27 * 8];
      const __half2* hp2 = (const __half2*)&hv2;
      #pragma unroll
      for (int g = 0; g < 4; g++) pk4(sB[g][1], hp2, acc[g][0], acc[g][1], acc[g][2], acc[g][3]);
    }
    // prefetch D(30,31) into sB
    #pragma unroll
    for (int g = 0; g < 4; g++){
      int row = tid + g * 256;
      sB[g][0] = wp4[30 * 1024 + row];
      sB[g][1] = wp4[31 * 1024 + row];
    }
    {
      uint4 hv = *(const uint4*)&hc[28 * 8];
      const __half2* hp = (const __half2*)&hv;
      #pragma unroll
      for (int g = 0; g < 4; g++) pk4(sA[g][0], hp, acc[g][0], acc[g][1], acc[g][2], acc[g][3]);
      uint4 hv2 = *(const uint4*)&hc[29 * 8];
      const __half2* hp2 = (const __half2*)&hv2;
      #pragma unroll
      for (int g = 0; g < 4; g++) pk4(sA[g][1], hp2, acc[g][0], acc[g][1], acc[g][2], acc[g][3]);
      uint4 hv3 = *(const uint4*)&hc[30 * 8];
      const __half2* hp3 = (const __half2*)&hv3;
      #pragma unroll
      for (int g = 0; g < 4; g++) pk4(sB[g][0], hp3, acc[g][0], acc[g][1], acc[g][2], acc[g][3]);
      uint4 hv4 = *(const uint4*)&hc[31 * 8];
      const __half2* hp4 = (const __half2*)&hv4;
      #pragma unroll
      for (int g = 0; g < 4; g++) pk4(sB[g][1], hp4, acc[g][0], acc[g][1], acc[g][2], acc[g][3]);
    }
    #pragma unroll
    for (int g = 0; g < 4; g++) fa[g] += flushacc(acc[g][0], acc[g][1], acc[g][2], acc[g][3]);

    // gates: rows t(i), t+256(f), t+512(g), t+768(o)
    float iv = sigm(fa[0] + xv0);
    float fv = sigm(fa[1] + xv1);
    float gv = tanh_fast(fa[2] + xv2);
    float ov = sigm(fa[3] + xv3);
    cc = fv * cc + iv * gv;
    float h = ov * tanh_fast(cc);
    hb[(cur ^ 1) * 256 + tid] = __float2half(h);
    rbp[(size_t)s * 512 + tid] = h;
    __syncthreads();
    cur ^= 1;
  }
}

// ---- K3: feats = rnn_out @ lin_W.T + lin_b  (one thread per (row,col)), rnn f32
__global__ void feat_gemv(const float* __restrict__ rnn,
    const float* __restrict__ linW, const float* __restrict__ linb,
    float* __restrict__ feats){
  int id = blockIdx.x * 256 + threadIdx.x;
  if (id >= BB * SS * KK) return;
  int row = id / 20;
  int col = id - row * 20;
  const float* rr = rnn + (size_t)row * 512;
  const float* wr = linW + col * 512;
  float acc = linb[col];
  for (int k8 = 0; k8 < 64; k8++){
    float4 ra = *(const float4*)(rr + k8 * 8);
    float4 rb = *(const float4*)(rr + k8 * 8 + 4);
    float4 wa = *(const float4*)(wr + k8 * 8);
    float4 wb = *(const float4*)(wr + k8 * 8 + 4);
    acc += ra.x * wa.x + ra.y * wa.y + ra.z * wa.z + ra.w * wa.w
         + rb.x * wb.x + rb.y * wb.y + rb.z * wb.z + rb.w * wb.w;
  }
  feats[id] = acc;
}

// ---- K4: CRF numerator + forward scan. One WG (1 wave) per batch.
__global__ __launch_bounds__(64) void crf_kernel(const int* __restrict__ tags,
    const int* __restrict__ lengths, const float* __restrict__ trans,
    const float* __restrict__ feats, float* __restrict__ out){
  int b = blockIdx.x, tid = threadIdx.x;
  __shared__ float tr[400];
  __shared__ float sc[20];
  for (int i = tid; i < 400; i += 64) tr[i] = trans[i];
  __syncthreads();
  int l = lengths[b];
  const int* tg = tags + b * SS;
  const float* fb = feats + (size_t)b * SS * 20;
  // numerator
  float p = 0.f;
  for (int s = tid; s < SS; s += 64){
    if (s < l){
      int cur = tg[s];
      int prev = s ? tg[s - 1] : SOS_IDX;
      p += fb[s * 20 + cur] + tr[cur * 20 + prev];
    }
  }
  #pragma unroll
  for (int off = 32; off; off >>= 1) p += __shfl_down(p, off);
  if (tid < 20) sc[tid] = (tid == SOS_IDX) ? 0.f : NEGV;
  __syncthreads();
  float em = (tid < 20 && l > 0) ? fb[tid] : 0.f;   // prefetched emission for s=0
  for (int s = 0; s < l; s++){
    float em_nxt = (tid < 20 && (s + 1) < l) ? fb[(s + 1) * 20 + tid] : 0.f;
    float nv = 0.f;
    if (tid < 20){
      const float* trow = &tr[tid * 20];
      float v[20];
      float m = -1e30f;
      #pragma unroll
      for (int jj = 0; jj < 20; jj++){ v[jj] = sc[jj] + trow[jj]; m = fmaxf(m, v[jj]); }
      float ssum = 0.f;
      #pragma unroll
      for (int jj = 0; jj < 20; jj++) ssum += __expf(v[jj] - m);
      nv = em + m + __logf(ssum);
    }
    __syncthreads();
    if (tid < 20) sc[tid] = nv;
    __syncthreads();
    em = em_nxt;
  }
  if (tid == 0){
    float m = -1e30f;
    #pragma unroll
    for (int i = 0; i < 20; i++) m = fmaxf(m, sc[i]);
    float ssum = 0.f;
    #pragma unroll
    for (int i = 0; i < 20; i++) ssum += __expf(sc[i] - m);
    out[b] = (m + __logf(ssum)) - p;
  }
}

extern "C" void kernel_launch(void* const* d_in, const int* in_sizes, int n_in,
                              void* d_out, int out_size, void* d_ws, size_t ws_size,
                              hipStream_t stream){
  const int*   word_seq = (const int*)d_in[0];
  const int*   tags     = (const int*)d_in[1];
  const int*   lengths  = (const int*)d_in[2];
  const float* embed    = (const float*)d_in[3];
  const float* wih_f    = (const float*)d_in[4];
  const float* whh_f    = (const float*)d_in[5];
  const float* b_f      = (const float*)d_in[6];
  const float* wih_b    = (const float*)d_in[7];
  const float* whh_b    = (const float*)d_in[8];
  const float* b_b      = (const float*)d_in[9];
  const float* linW     = (const float*)d_in[10];
  const float* linb     = (const float*)d_in[11];
  const float* trans    = (const float*)d_in[12];
  float* out = (float*)d_out;

  // workspace layout (~196.5 MiB); xg is 128 MiB (2*64*512*1024 f16)
  char* ws = (char*)d_ws;
  __half* wp    = (__half*)ws;                                         // 1 MiB
  float*  wt    = (float*)(ws + (1ull << 20));                         // 1 MiB
  __half* xg    = (__half*)(ws + (2ull << 20));                        // 128 MiB
  float*  rnn   = (float*)(ws + (2ull << 20) + (128ull << 20));        // 64 MiB
  float*  feats = (float*)(ws + (2ull << 20) + (192ull << 20));        // 2.5 MiB

  (void)hipFuncSetAttribute((const void*)lstm_seq,
        hipFuncAttributeMaxDynamicSharedMemorySize, 132096);

  prep_whh<<<dim3(2048), dim3(256), 0, stream>>>(whh_f, whh_b, wp);
  prep_wih<<<dim3(1024), dim3(256), 0, stream>>>(wih_f, wih_b, wt);
  xg_gemm<<<dim3(4096), dim3(256), 0, stream>>>(word_seq, embed, wt, b_f, b_b, xg);
  lstm_seq<<<dim3(128), dim3(256), 132096, stream>>>(lengths, wp, xg, rnn);
  feat_gemv<<<dim3(2560), dim3(256), 0, stream>>>(rnn, linW, linb, feats);
  crf_kernel<<<dim3(64), dim3(64), 0, stream>>>(tags, lengths, trans, feats, out);
}

// Round 6
// 1630.947 us; speedup vs baseline: 1.7173x; 1.7173x over previous
//
#include <hip/hip_runtime.h>
#include <hip/hip_fp16.h>
#include <stdint.h>

// Problem constants
#define BB 64
#define SS 512
#define EE 128
#define HH 256
#define KK 20
#define NEGV -9999.0f
#define SOS_IDX 19

typedef unsigned int u32;

__device__ __forceinline__ float sigm(float x){ return 1.0f / (1.0f + __expf(-x)); }
__device__ __forceinline__ float tanh_fast(float x){
  float e = __expf(2.f * x);          // x->+inf: e=inf -> 1; x->-inf: e=0 -> -1
  return 1.f - 2.f / (e + 1.f);
}

// 4 packed fma: w (uint4 = 8 f16) * h (4 half2) -> 4 half2 accs
__device__ __forceinline__ void pk4(uint4 w, const __half2* hp,
                                    __half2& a0, __half2& a1, __half2& a2, __half2& a3){
  __half2 w0 = *(__half2*)&w.x, w1 = *(__half2*)&w.y, w2 = *(__half2*)&w.z, w3 = *(__half2*)&w.w;
  a0 = __hfma2(w0, hp[0], a0);
  a1 = __hfma2(w1, hp[1], a1);
  a2 = __hfma2(w2, hp[2], a2);
  a3 = __hfma2(w3, hp[3], a3);
}
__device__ __forceinline__ float flushacc(__half2& a0, __half2& a1, __half2& a2, __half2& a3){
  float2 f0 = __half22float2(a0), f1 = __half22float2(a1);
  float2 f2 = __half22float2(a2), f3 = __half22float2(a3);
  __half2 z = __floats2half2_rn(0.f, 0.f);
  a0 = z; a1 = z; a2 = z; a3 = z;
  return ((f0.x + f0.y) + (f1.x + f1.y)) + ((f2.x + f2.y) + (f3.x + f3.y));
}

// ---- K0a: pack W_hh (f32 [1024][256]) -> f16 wp[d][chunk(32)][row(1024)][8]
__global__ void prep_whh(const float* __restrict__ whh_f, const float* __restrict__ whh_b,
                         __half* __restrict__ wp){
  int id = blockIdx.x * 256 + threadIdx.x;      // 2*1024*256 = 524288
  if (id >= 524288) return;
  int d = id >> 18;
  int rem = id & 262143;
  int row = rem >> 8;
  int k = rem & 255;
  const float* w = d ? whh_b : whh_f;
  wp[(((size_t)d * 32 + (k >> 3)) * 1024 + row) * 8 + (k & 7)] = __float2half(w[row * 256 + k]);
}

// ---- K0b: transpose W_ih -> wt[k(128)][2048] f32 (cols 0..1023 fwd, 1024..2047 bwd)
__global__ void prep_wih(const float* __restrict__ wih_f, const float* __restrict__ wih_b,
                         float* __restrict__ wt){
  int id = blockIdx.x * 256 + threadIdx.x;      // 2*1024*128 = 262144
  if (id >= 262144) return;
  int d = id >> 17;
  int rem = id & 131071;
  int col = rem >> 7;
  int k = rem & 127;
  const float* w = d ? wih_b : wih_f;
  wt[(size_t)k * 2048 + d * 1024 + col] = w[col * 128 + k];
}

// ---- K1: xg = embed[word] @ W_ih.T + b, both dirs, stored f16.
__global__ __launch_bounds__(256) void xg_gemm(const int* __restrict__ word_seq,
    const float* __restrict__ embed, const float* __restrict__ wt,
    const float* __restrict__ b_f, const float* __restrict__ b_b,
    __half* __restrict__ xg){
  __shared__ __align__(16) float xs[16][128];
  int rb = blockIdx.x >> 1, cb = blockIdx.x & 1;
  int tid = threadIdx.x;
  {
    int r = tid >> 4, kq = (tid & 15) * 8;
    int bs = rb * 16 + r;
    int w = word_seq[bs];
    const float* er = embed + (size_t)w * 128 + kq;
    float4 a = *(const float4*)er;
    float4 b = *(const float4*)(er + 4);
    *(float4*)&xs[r][kq] = a;
    *(float4*)&xs[r][kq + 4] = b;
  }
  __syncthreads();
  int co = tid * 4;
  const float* bias = cb ? b_b : b_f;
  float4 bv = *(const float4*)(bias + co);
  float4 acc[16];
  #pragma unroll
  for (int r = 0; r < 16; r++) acc[r] = bv;
  const float* wptr = wt + cb * 1024 + co;
  for (int k = 0; k < 128; k++){
    float4 w4 = *(const float4*)(wptr + (size_t)k * 2048);
    #pragma unroll
    for (int r = 0; r < 16; r++){
      float xv = xs[r][k];
      acc[r].x += xv * w4.x; acc[r].y += xv * w4.y;
      acc[r].z += xv * w4.z; acc[r].w += xv * w4.w;
    }
  }
  __half* base = xg + (size_t)cb * ((size_t)BB * SS * 1024);
  #pragma unroll
  for (int r = 0; r < 16; r++){
    int bs = rb * 16 + r;
    __half* o = base + (size_t)bs * 1024 + co;
    __half2 p0 = __floats2half2_rn(acc[r].x, acc[r].y);
    __half2 p1 = __floats2half2_rn(acc[r].z, acc[r].w);
    uint2 st; st.x = *(u32*)&p0; st.y = *(u32*)&p1;
    *(uint2*)o = st;
  }
}

// ---- K2: sequential LSTM, one WG (512 thr = 8 waves, 2 waves/SIMD) per (batch, dir).
// Thread pair (2u, 2u+1) owns unit u: lane 2u has rows {u, u+512} = gates (i,g),
// lane 2u+1 has rows {u+256, u+768} = gates (f,o). Gate exchange via __shfl_xor(.,1);
// both lanes redundantly update c (identical) -> ONE barrier per step.
// Weight tiers per row (32 chunks of 8 f16):
//   chunks 0..16  : VGPR (2 rows x 17 = 34 uint4 = 136 regs; cap 256 at 2 waves/EU)
//   chunks 17..25 : LDS thread-private, slot-contiguous 16B stride (conflict-free), 144 KB
//   chunks 26..31 : streamed from L2, all issued at step top (12 uint4 in flight)
// h: f16 double-buffer in LDS (2x512 B), b128 broadcast reads.
__global__ __launch_bounds__(512, 2) void lstm_seq(const int* __restrict__ lengths,
    const __half* __restrict__ wp, const __half* __restrict__ xg,
    float* __restrict__ rnn){
  extern __shared__ __align__(16) char smem[];
  u32*    wl = (u32*)smem;                       // 9 chunks * 2 rows * 512 thr * 16 B = 147456
  __half* hb = (__half*)(smem + 147456);         // 2 * 256 f16 = 1024 B

  int bx = blockIdx.x;
  int b = bx & 63, d = bx >> 6;
  int tid = threadIdx.x;
  int u = tid >> 1, q = tid & 1;
  int row0 = u + q * 256;            // gate i (q=0) / f (q=1)
  int row1 = row0 + 512;             // gate g (q=0) / o (q=1)
  int l = lengths[b];
  const uint4* wp4 = (const uint4*)(wp + (size_t)d * (32 * 1024 * 8));

  // VGPR tier: chunks 0..16
  uint4 wr0[17], wr1[17];
  #pragma unroll
  for (int c = 0; c < 17; c++){ wr0[c] = wp4[c * 1024 + row0]; wr1[c] = wp4[c * 1024 + row1]; }
  // LDS tier: chunks 17..25, slot = (c-17)*2 + r
  #pragma unroll
  for (int c = 0; c < 9; c++){
    *(uint4*)&wl[((c * 2 + 0) * 512 + tid) * 4] = wp4[(17 + c) * 1024 + row0];
    *(uint4*)&wl[((c * 2 + 1) * 512 + tid) * 4] = wp4[(17 + c) * 1024 + row1];
  }
  if (tid < 256) hb[tid] = __float2half(0.f);    // buffer 0
  float cc = 0.f;
  const __half* xgd = xg + ((size_t)d * BB * SS + (size_t)b * SS) * 1024;
  float* rbp = rnn + (size_t)b * SS * 512 + d * 256;
  for (int i = tid; i < (SS - l) * 256; i += 512){
    int s = l + (i >> 8), j = i & 255;
    rbp[(size_t)s * 512 + j] = 0.f;
  }
  // per-lane nonlinearity constants for gate row1: q=0 -> tanh via 2*sigm(2x)-1
  float nsc = q ? 1.f : 2.f;
  float nmu = q ? 1.f : 2.f;
  float nad = q ? 0.f : -1.f;
  int cur = 0;
  __syncthreads();

  for (int t = 0; t < l; t++){
    int s = d ? (l - 1 - t) : t;
    const __half* xr = xgd + (size_t)s * 1024;
    float xv0 = __half2float(xr[row0]);
    float xv1 = __half2float(xr[row1]);
    // stream tier: issue all 12 loads now, consume after VGPR+LDS tiers
    uint4 s0[6], s1[6];
    #pragma unroll
    for (int c = 0; c < 6; c++){
      s0[c] = wp4[(26 + c) * 1024 + row0];
      s1[c] = wp4[(26 + c) * 1024 + row1];
    }
    const __half* hc = &hb[cur * 256];
    __half2 z = __floats2half2_rn(0.f, 0.f);
    __half2 a00 = z, a01 = z, a02 = z, a03 = z;
    __half2 a10 = z, a11 = z, a12 = z, a13 = z;
    float fa0, fa1;
    // phase V: chunks 0..16 from VGPR
    #pragma unroll
    for (int c = 0; c < 17; c++){
      uint4 hv = *(const uint4*)&hc[c * 8];
      const __half2* hp = (const __half2*)&hv;
      pk4(wr0[c], hp, a00, a01, a02, a03);
      pk4(wr1[c], hp, a10, a11, a12, a13);
    }
    fa0 = flushacc(a00, a01, a02, a03);
    fa1 = flushacc(a10, a11, a12, a13);
    // phase L: chunks 17..25 from LDS
    #pragma unroll
    for (int c = 0; c < 9; c++){
      uint4 hv = *(const uint4*)&hc[(17 + c) * 8];
      const __half2* hp = (const __half2*)&hv;
      uint4 w0 = *(const uint4*)&wl[((c * 2 + 0) * 512 + tid) * 4];
      uint4 w1 = *(const uint4*)&wl[((c * 2 + 1) * 512 + tid) * 4];
      pk4(w0, hp, a00, a01, a02, a03);
      pk4(w1, hp, a10, a11, a12, a13);
    }
    fa0 += flushacc(a00, a01, a02, a03);
    fa1 += flushacc(a10, a11, a12, a13);
    // phase S: chunks 26..31 streamed
    #pragma unroll
    for (int c = 0; c < 6; c++){
      uint4 hv = *(const uint4*)&hc[(26 + c) * 8];
      const __half2* hp = (const __half2*)&hv;
      pk4(s0[c], hp, a00, a01, a02, a03);
      pk4(s1[c], hp, a10, a11, a12, a13);
    }
    fa0 += flushacc(a00, a01, a02, a03);
    fa1 += flushacc(a10, a11, a12, a13);

    fa0 += xv0;
    fa1 += xv1;
    float g0 = sigm(fa0);                          // i (q=0) / f (q=1)
    float g1 = sigm(nsc * fa1) * nmu + nad;        // g=tanh (q=0) / o=sigm (q=1)
    float p0 = __shfl_xor(g0, 1);                  // q=0 lane: f ; q=1 lane: i
    float p1 = __shfl_xor(g1, 1);                  // q=0 lane: o ; q=1 lane: g
    float iv = q ? p0 : g0;
    float fv = q ? g0 : p0;
    float gv = q ? p1 : g1;
    float ov = q ? g1 : p1;
    cc = fv * cc + iv * gv;
    float h = ov * tanh_fast(cc);
    if (q) rbp[(size_t)s * 512 + u] = h;
    else   hb[(cur ^ 1) * 256 + u] = __float2half(h);
    __syncthreads();
    cur ^= 1;
  }
}

// ---- K3: feats = rnn_out @ lin_W.T + lin_b  (one thread per (row,col)), rnn f32
__global__ void feat_gemv(const float* __restrict__ rnn,
    const float* __restrict__ linW, const float* __restrict__ linb,
    float* __restrict__ feats){
  int id = blockIdx.x * 256 + threadIdx.x;
  if (id >= BB * SS * KK) return;
  int row = id / 20;
  int col = id - row * 20;
  const float* rr = rnn + (size_t)row * 512;
  const float* wr = linW + col * 512;
  float acc = linb[col];
  for (int k8 = 0; k8 < 64; k8++){
    float4 ra = *(const float4*)(rr + k8 * 8);
    float4 rb = *(const float4*)(rr + k8 * 8 + 4);
    float4 wa = *(const float4*)(wr + k8 * 8);
    float4 wb = *(const float4*)(wr + k8 * 8 + 4);
    acc += ra.x * wa.x + ra.y * wa.y + ra.z * wa.z + ra.w * wa.w
         + rb.x * wb.x + rb.y * wb.y + rb.z * wb.z + rb.w * wb.w;
  }
  feats[id] = acc;
}

// ---- K4: CRF numerator + forward scan. One WG (1 wave) per batch.
__global__ __launch_bounds__(64) void crf_kernel(const int* __restrict__ tags,
    const int* __restrict__ lengths, const float* __restrict__ trans,
    const float* __restrict__ feats, float* __restrict__ out){
  int b = blockIdx.x, tid = threadIdx.x;
  __shared__ float tr[400];
  __shared__ float sc[20];
  for (int i = tid; i < 400; i += 64) tr[i] = trans[i];
  __syncthreads();
  int l = lengths[b];
  const int* tg = tags + b * SS;
  const float* fb = feats + (size_t)b * SS * 20;
  // numerator
  float p = 0.f;
  for (int s = tid; s < SS; s += 64){
    if (s < l){
      int cur = tg[s];
      int prev = s ? tg[s - 1] : SOS_IDX;
      p += fb[s * 20 + cur] + tr[cur * 20 + prev];
    }
  }
  #pragma unroll
  for (int off = 32; off; off >>= 1) p += __shfl_down(p, off);
  if (tid < 20) sc[tid] = (tid == SOS_IDX) ? 0.f : NEGV;
  __syncthreads();
  float em = (tid < 20 && l > 0) ? fb[tid] : 0.f;   // prefetched emission for s=0
  for (int s = 0; s < l; s++){
    float em_nxt = (tid < 20 && (s + 1) < l) ? fb[(s + 1) * 20 + tid] : 0.f;
    float nv = 0.f;
    if (tid < 20){
      const float* trow = &tr[tid * 20];
      float v[20];
      float m = -1e30f;
      #pragma unroll
      for (int jj = 0; jj < 20; jj++){ v[jj] = sc[jj] + trow[jj]; m = fmaxf(m, v[jj]); }
      float ssum = 0.f;
      #pragma unroll
      for (int jj = 0; jj < 20; jj++) ssum += __expf(v[jj] - m);
      nv = em + m + __logf(ssum);
    }
    __syncthreads();
    if (tid < 20) sc[tid] = nv;
    __syncthreads();
    em = em_nxt;
  }
  if (tid == 0){
    float m = -1e30f;
    #pragma unroll
    for (int i = 0; i < 20; i++) m = fmaxf(m, sc[i]);
    float ssum = 0.f;
    #pragma unroll
    for (int i = 0; i < 20; i++) ssum += __expf(sc[i] - m);
    out[b] = (m + __logf(ssum)) - p;
  }
}

extern "C" void kernel_launch(void* const* d_in, const int* in_sizes, int n_in,
                              void* d_out, int out_size, void* d_ws, size_t ws_size,
                              hipStream_t stream){
  const int*   word_seq = (const int*)d_in[0];
  const int*   tags     = (const int*)d_in[1];
  const int*   lengths  = (const int*)d_in[2];
  const float* embed    = (const float*)d_in[3];
  const float* wih_f    = (const float*)d_in[4];
  const float* whh_f    = (const float*)d_in[5];
  const float* b_f      = (const float*)d_in[6];
  const float* wih_b    = (const float*)d_in[7];
  const float* whh_b    = (const float*)d_in[8];
  const float* b_b      = (const float*)d_in[9];
  const float* linW     = (const float*)d_in[10];
  const float* linb     = (const float*)d_in[11];
  const float* trans    = (const float*)d_in[12];
  float* out = (float*)d_out;

  // workspace layout (~196.5 MiB); xg is 128 MiB (2*64*512*1024 f16)
  char* ws = (char*)d_ws;
  __half* wp    = (__half*)ws;                                         // 1 MiB
  float*  wt    = (float*)(ws + (1ull << 20));                         // 1 MiB
  __half* xg    = (__half*)(ws + (2ull << 20));                        // 128 MiB
  float*  rnn   = (float*)(ws + (2ull << 20) + (128ull << 20));        // 64 MiB
  float*  feats = (float*)(ws + (2ull << 20) + (192ull << 20));        // 2.5 MiB

  (void)hipFuncSetAttribute((const void*)lstm_seq,
        hipFuncAttributeMaxDynamicSharedMemorySize, 148480);

  prep_whh<<<dim3(2048), dim3(256), 0, stream>>>(whh_f, whh_b, wp);
  prep_wih<<<dim3(1024), dim3(256), 0, stream>>>(wih_f, wih_b, wt);
  xg_gemm<<<dim3(4096), dim3(256), 0, stream>>>(word_seq, embed, wt, b_f, b_b, xg);
  lstm_seq<<<dim3(128), dim3(512), 148480, stream>>>(lengths, wp, xg, rnn);
  feat_gemv<<<dim3(2560), dim3(256), 0, stream>>>(rnn, linW, linb, feats);
  crf_kernel<<<dim3(64), dim3(64), 0, stream>>>(tags, lengths, trans, feats, out);
}